// Round 10
// baseline (431.218 us; speedup 1.0000x reference)
//
#include <hip/hip_runtime.h>
#include <cstdint>
#include <cstddef>

#define NHEADS 16
#define HD 64
#define SEQ 2048
#define BATCH 4
#define DIMSZ 1024
#define MR (BATCH * SEQ) /* 8192 */

typedef __attribute__((ext_vector_type(8))) short short8;
typedef __attribute__((ext_vector_type(4))) short short4v;
typedef __attribute__((ext_vector_type(4))) float f32x4;

typedef __attribute__((address_space(1))) const unsigned int as1_u32;
typedef __attribute__((address_space(3))) unsigned int as3_u32;

__device__ __forceinline__ unsigned short f2bf(float x) {
  union { float f; unsigned int u; } v; v.f = x;
  unsigned int r = v.u + 0x7FFFu + ((v.u >> 16) & 1u);
  return (unsigned short)(r >> 16);
}

__device__ __forceinline__ f32x4 mfma16(short8 a, short8 b, f32x4 c) {
  return __builtin_amdgcn_mfma_f32_16x16x32_bf16(a, b, c, 0, 0, 0);
}

__device__ __forceinline__ void gload_lds16(const void* g, void* l) {
  __builtin_amdgcn_global_load_lds((as1_u32*)g, (as3_u32*)l, 16, 0, 0);
}

// XOR swizzle for 128B-row LDS tiles (bits 4-6; involution).
__device__ __forceinline__ int swzfn(int r) { return ((r ^ (r >> 3)) & 7) << 4; }

// ---------------- fp32 -> bf16 convert ----------------
struct Cvt7 {
  const float* s[7];
  unsigned short* d[7];
  int n4[7];
};

__global__ __launch_bounds__(256) void cvt7_k(Cvt7 a) {
  const int t = blockIdx.y;
  const float4* s = (const float4*)a.s[t];
  ushort4* d = (ushort4*)a.d[t];
  const int n4 = a.n4[t];
  for (int i = blockIdx.x * 256 + threadIdx.x; i < n4; i += gridDim.x * 256) {
    float4 f = s[i];
    ushort4 u;
    u.x = f2bf(f.x); u.y = f2bf(f.y); u.z = f2bf(f.z); u.w = f2bf(f.w);
    d[i] = u;
  }
}

// ---------------- GEMM: C[M,N] = A[M,K] * Bt[N,K]^T + bias ----------------
// 128x128 tile, BK=32, 4 waves; 2-phase prefetch pipeline (dbuf LDS, one
// barrier per K-step; stage(k+1) issued before compute(k)) — T3-minimum.
struct GemmArgs {
  const unsigned short* A[3];
  const unsigned short* Bt[3];
  const float* bias[3];
  unsigned short* Cb[3];
  float* Cf[3];
  float scale[3];
  int vt[3];  // 1 => write bf16 output transposed per-head: vt[bh][d][kv]
};

template <bool BF16OUT>
__global__ __launch_bounds__(256) void gemm_bt_k(GemmArgs g) {
  const int z = blockIdx.z;
  const unsigned short* __restrict__ A = g.A[z];
  const unsigned short* __restrict__ Bt = g.Bt[z];
  const float* __restrict__ bias = g.bias[z];

  __shared__ unsigned short As[2][128 * 32];
  __shared__ unsigned short Bs[2][128 * 32];

  const int tid = threadIdx.x;
  const int lane = tid & 63;
  const int wave = tid >> 6;
  const int bm = blockIdx.x * 128;
  const int bn = blockIdx.y * 128;
  const int wm = (wave >> 1) * 64;
  const int wn = (wave & 1) * 64;

  const int srow = wave * 16 + (lane >> 2);
  const int scol = (lane & 3) * 8;
  const unsigned short* a_src = A + (size_t)(bm + srow) * DIMSZ + scol;
  const unsigned short* b_src = Bt + (size_t)(bn + srow) * DIMSZ + scol;
  const int dstoff = wave * 16 * 64;  // byte offset of this wave's stripe

  const int fr = lane & 15;
  const int fk = (lane >> 4) * 8;

  f32x4 acc[4][4];
#pragma unroll
  for (int m = 0; m < 4; m++)
#pragma unroll
    for (int n = 0; n < 4; n++) acc[m][n] = (f32x4){0.f, 0.f, 0.f, 0.f};

  auto stageg = [&](int k0, int buf) {
    gload_lds16(a_src + k0, (char*)As[buf] + dstoff);
    gload_lds16(a_src + (size_t)64 * DIMSZ + k0, (char*)As[buf] + dstoff + 64 * 64);
    gload_lds16(b_src + k0, (char*)Bs[buf] + dstoff);
    gload_lds16(b_src + (size_t)64 * DIMSZ + k0, (char*)Bs[buf] + dstoff + 64 * 64);
  };

  stageg(0, 0);
  __syncthreads();
  int cur = 0;

  for (int k0 = 0; k0 < DIMSZ; k0 += 32) {
    if (k0 + 32 < DIMSZ) stageg(k0 + 32, cur ^ 1);

    const unsigned short* Ac = As[cur];
    const unsigned short* Bc = Bs[cur];
    short8 af[4], bfr[4];
#pragma unroll
    for (int m = 0; m < 4; m++) af[m] = *(const short8*)&Ac[(wm + m * 16 + fr) * 32 + fk];
#pragma unroll
    for (int n = 0; n < 4; n++) bfr[n] = *(const short8*)&Bc[(wn + n * 16 + fr) * 32 + fk];
#pragma unroll
    for (int m = 0; m < 4; m++)
#pragma unroll
      for (int n = 0; n < 4; n++) acc[m][n] = mfma16(af[m], bfr[n], acc[m][n]);

    __syncthreads();  // staged buf ready; cur buf free for next stage
    cur ^= 1;
  }

  // epilogue: C/D layout col=lane&15, row=(lane>>4)*4+j (m89/m91-verified)
  const int r4 = (lane >> 4) * 4;
  const float sc = g.scale[z];
  if (g.vt[z]) {
    // write V^T per-head: vt[(b*16+h)*64 + d][kv], 4 consecutive rows packed
    unsigned short* vtp = g.Cb[z];
#pragma unroll
    for (int n = 0; n < 4; n++) {
      const int c = bn + wn + n * 16 + fr;
      const float bv = bias[c];
#pragma unroll
      for (int m = 0; m < 4; m++) {
        const int rr = bm + wm + m * 16 + r4;
        ushort4 u;
        u.x = f2bf((acc[m][n][0] + bv) * sc);
        u.y = f2bf((acc[m][n][1] + bv) * sc);
        u.z = f2bf((acc[m][n][2] + bv) * sc);
        u.w = f2bf((acc[m][n][3] + bv) * sc);
        const size_t idx =
            ((size_t)((rr >> 11) * NHEADS + (c >> 6)) * HD + (c & 63)) * SEQ + (rr & (SEQ - 1));
        *(ushort4*)&vtp[idx] = u;
      }
    }
  } else {
#pragma unroll
    for (int n = 0; n < 4; n++) {
      const int c = bn + wn + n * 16 + fr;
      const float bv = bias[c];
#pragma unroll
      for (int m = 0; m < 4; m++) {
#pragma unroll
        for (int j = 0; j < 4; j++) {
          const int r = bm + wm + m * 16 + r4 + j;
          const float val = (acc[m][n][j] + bv) * sc;
          if (BF16OUT)
            g.Cb[z][(size_t)r * DIMSZ + c] = f2bf(val);
          else
            g.Cf[z][(size_t)r * DIMSZ + c] = val;
        }
      }
    }
  }
}

// ---------------- fused attention ----------------
// grid (SEQ/128, 64 bh), 8 waves x 16 q-rows. Swapped QK^T; online-max softmax
// in exp2 domain (Q pre-scaled by 0.125*log2e); defer-rescale THR=11 (log2);
// pi-permuted PV (A-frag lane-local, no shuffles); K/V^T via global_load_lds
// (pre-swizzled source), double-buffered.
__global__ __launch_bounds__(512) void attn_k(const unsigned short* __restrict__ q,
                                              const unsigned short* __restrict__ k,
                                              const unsigned short* __restrict__ vt,
                                              unsigned short* __restrict__ o) {
  const int tid = threadIdx.x;
  const int lane = tid & 63;
  const int wave = tid >> 6;  // 0..7
  const int bh = blockIdx.y;
  const int b = bh >> 4;
  const int h = bh & 15;
  const int q0 = blockIdx.x * 128;

  __shared__ unsigned short Ks[2][64 * 64];
  __shared__ unsigned short Vs[2][64 * 64];

  const int fr = lane & 15;
  const int g4 = lane >> 4;
  const int fkb = g4 * 16;

  // Q fragments (Q pre-scaled by 0.125*log2e in the projection GEMM)
  const size_t qrow = (size_t)b * SEQ + q0 + wave * 16 + fr;
  const unsigned short* qp = q + qrow * DIMSZ + h * HD + g4 * 8;
  const short8 qa0 = *(const short8*)(qp);
  const short8 qa1 = *(const short8*)(qp + 32);

  float m_run = -1e30f, l_run = 0.f;
  f32x4 oacc[4];
#pragma unroll
  for (int n = 0; n < 4; n++) oacc[n] = (f32x4){0.f, 0.f, 0.f, 0.f};

  // loop-invariant LDS read offsets
  int koff[4][2];   // QK^T: b128 reads of K rows
  int voff[4][4];   // PV: b64 reads of V^T rows at pi-slot offsets
#pragma unroll
  for (int n = 0; n < 4; n++) {
    const int row = fr + 16 * n;
    const int swz = swzfn(row);
    koff[n][0] = (row * 128 + fkb) ^ swz;
    koff[n][1] = (row * 128 + 64 + fkb) ^ swz;
#pragma unroll
    for (int c = 0; c < 4; c++) voff[n][c] = (row * 128 + (c * 32 + 8 * g4)) ^ swz;
  }

  // staging: 8 waves x 8 rows; linear LDS dest, pre-swizzled global source
  const int klrow = lane >> 3;
  const int kcb = (lane & 7) * 16;
  const int srow = wave * 8 + klrow;  // 0..63
  const int scol = (kcb ^ swzfn(srow)) >> 1;
  const unsigned short* ksrc =
      k + (size_t)b * SEQ * DIMSZ + h * HD + (size_t)srow * DIMSZ + scol;
  const unsigned short* vsrc =
      vt + (size_t)bh * HD * SEQ + (size_t)srow * SEQ + scol;

  auto stage = [&](int t, int buf) {
    const size_t kv0 = (size_t)t * 64;
    gload_lds16(ksrc + kv0 * DIMSZ, (char*)Ks[buf] + wave * 1024);
    gload_lds16(vsrc + kv0, (char*)Vs[buf] + wave * 1024);
  };

  stage(0, 0);
  __syncthreads();
  int cur = 0;

  for (int t = 0; t < SEQ / 64; ++t) {
    if (t + 1 < SEQ / 64) stage(t + 1, cur ^ 1);

    const char* Kc = (const char*)Ks[cur];
    const char* Vc = (const char*)Vs[cur];

    // S^T = K.Q^T : lane (fr,g4) holds S[kv = 16n + 4g4 + jj][q = fr] (log2 units)
    f32x4 s[4];
#pragma unroll
    for (int n = 0; n < 4; n++) {
      const short8 kb0 = *(const short8*)(Kc + koff[n][0]);
      const short8 kb1 = *(const short8*)(Kc + koff[n][1]);
      f32x4 tacc = (f32x4){0.f, 0.f, 0.f, 0.f};
      tacc = mfma16(kb0, qa0, tacc);
      tacc = mfma16(kb1, qa1, tacc);
      s[n] = tacc;
    }

    // online softmax (log2 domain), defer-rescale when max growth <= THR
    float pm = -1e30f;
#pragma unroll
    for (int n = 0; n < 4; n++)
#pragma unroll
      for (int jj = 0; jj < 4; jj++) pm = fmaxf(pm, s[n][jj]);
    pm = fmaxf(pm, __shfl_xor(pm, 16));
    pm = fmaxf(pm, __shfl_xor(pm, 32));
    if (__any(pm > m_run + 11.0f)) {
      const float mn = fmaxf(m_run, pm);
      const float sf = exp2f(m_run - mn);
      m_run = mn;
      l_run *= sf;
      float sfr[4];
#pragma unroll
      for (int jj = 0; jj < 4; jj++) sfr[jj] = __shfl(sf, 20 * g4 + jj);
#pragma unroll
      for (int n = 0; n < 4; n++)
#pragma unroll
        for (int jj = 0; jj < 4; jj++) oacc[n][jj] *= sfr[jj];
    }

    unsigned pu[4][2];
    float rs = 0.f;
#pragma unroll
    for (int n = 0; n < 4; n++) {
      const float p0 = exp2f(s[n][0] - m_run);
      const float p1 = exp2f(s[n][1] - m_run);
      const float p2 = exp2f(s[n][2] - m_run);
      const float p3 = exp2f(s[n][3] - m_run);
      rs += (p0 + p1) + (p2 + p3);
      pu[n][0] = (unsigned)f2bf(p0) | ((unsigned)f2bf(p1) << 16);
      pu[n][1] = (unsigned)f2bf(p2) | ((unsigned)f2bf(p3) << 16);
    }
    l_run += rs;  // per-lane partial (row-sum deferred to epilogue)

    // pi-permuted A-fragments: slot k=8*g4+e  <->  kv = (e<4 ? 4g4+e : 16+4g4+e-4)
    // (+32 for pa1) — exactly the kv values this lane already holds. No shuffles.
    union { unsigned u[4]; short8 v; } pa0, pa1;
    pa0.u[0] = pu[0][0]; pa0.u[1] = pu[0][1]; pa0.u[2] = pu[1][0]; pa0.u[3] = pu[1][1];
    pa1.u[0] = pu[2][0]; pa1.u[1] = pu[2][1]; pa1.u[2] = pu[3][0]; pa1.u[3] = pu[3][1];

    // O += P V, B-frag read at matching pi-slot offsets (two b64 per frag)
#pragma unroll
    for (int n = 0; n < 4; n++) {
      union { short4v h[2]; short8 v; } vb0, vb1;
      vb0.h[0] = *(const short4v*)(Vc + voff[n][0]);
      vb0.h[1] = *(const short4v*)(Vc + voff[n][1]);
      vb1.h[0] = *(const short4v*)(Vc + voff[n][2]);
      vb1.h[1] = *(const short4v*)(Vc + voff[n][3]);
      oacc[n] = mfma16(pa0.v, vb0.v, oacc[n]);
      oacc[n] = mfma16(pa1.v, vb1.v, oacc[n]);
    }

    __syncthreads();  // next-tile staging complete; cur buffer free
    cur ^= 1;
  }

  // epilogue: reduce l across the 4 g4 copies, then O /= l
  l_run += __shfl_xor(l_run, 16);
  l_run += __shfl_xor(l_run, 32);
  float inv[4];
#pragma unroll
  for (int jj = 0; jj < 4; jj++) inv[jj] = 1.f / __shfl(l_run, 20 * g4 + jj);
#pragma unroll
  for (int n = 0; n < 4; n++)
#pragma unroll
    for (int jj = 0; jj < 4; jj++) {
      const int row = q0 + wave * 16 + 4 * g4 + jj;
      o[((size_t)bh * SEQ + row) * HD + fr + 16 * n] = f2bf(oacc[n][jj] * inv[jj]);
    }
}

// ---------------- launcher ----------------
extern "C" void kernel_launch(void* const* d_in, const int* in_sizes, int n_in,
                              void* d_out, int out_size, void* d_ws, size_t ws_size,
                              hipStream_t stream) {
  (void)in_sizes; (void)n_in; (void)out_size; (void)ws_size;
  const float* query = (const float*)d_in[0];
  const float* key_i = (const float*)d_in[1];
  const float* value = (const float*)d_in[2];
  const float* Wq = (const float*)d_in[3];
  const float* bq = (const float*)d_in[4];
  const float* Wk = (const float*)d_in[5];
  const float* bk = (const float*)d_in[6];
  const float* Wv = (const float*)d_in[7];
  const float* bv = (const float*)d_in[8];
  const float* Wo = (const float*)d_in[9];
  const float* bo = (const float*)d_in[10];
  float* out = (float*)d_out;

  char* ws = (char*)d_ws;
  size_t off = 0;
  auto alloc = [&](size_t bytes) -> char* {
    char* p = ws + off;
    off += (bytes + 255) & ~(size_t)255;
    return p;
  };
  const size_t big = (size_t)MR * DIMSZ * 2;      // 16.78 MB
  const size_t wsz = (size_t)DIMSZ * DIMSZ * 2;   // 2.1 MB
  unsigned short* xq = (unsigned short*)alloc(big);
  unsigned short* xk = (unsigned short*)alloc(big);
  unsigned short* xv = (unsigned short*)alloc(big);
  unsigned short* wqb = (unsigned short*)alloc(wsz);
  unsigned short* wkb = (unsigned short*)alloc(wsz);
  unsigned short* wvb = (unsigned short*)alloc(wsz);
  unsigned short* wob = (unsigned short*)alloc(wsz);
  unsigned short* qb = (unsigned short*)alloc(big);
  unsigned short* kb = (unsigned short*)alloc(big);
  unsigned short* vtb = (unsigned short*)alloc(big);  // V^T per-head [bh][d][kv]
  unsigned short* ob = xq;  // xq dead after QKV GEMM

  // 1) convert inputs + weights to bf16
  Cvt7 ca;
  ca.s[0] = query; ca.d[0] = xq; ca.n4[0] = MR * DIMSZ / 4;
  ca.s[1] = key_i; ca.d[1] = xk; ca.n4[1] = MR * DIMSZ / 4;
  ca.s[2] = value; ca.d[2] = xv; ca.n4[2] = MR * DIMSZ / 4;
  ca.s[3] = Wq;    ca.d[3] = wqb; ca.n4[3] = DIMSZ * DIMSZ / 4;
  ca.s[4] = Wk;    ca.d[4] = wkb; ca.n4[4] = DIMSZ * DIMSZ / 4;
  ca.s[5] = Wv;    ca.d[5] = wvb; ca.n4[5] = DIMSZ * DIMSZ / 4;
  ca.s[6] = Wo;    ca.d[6] = wob; ca.n4[6] = DIMSZ * DIMSZ / 4;
  cvt7_k<<<dim3(1024, 7), 256, 0, stream>>>(ca);

  // 2) QKV projections (z-fused); Q pre-scaled by 0.125*log2e (exp2-domain
  //    softmax); V written transposed per-head
  GemmArgs gp;
  gp.A[0] = xq; gp.A[1] = xk; gp.A[2] = xv;
  gp.Bt[0] = wqb; gp.Bt[1] = wkb; gp.Bt[2] = wvb;
  gp.bias[0] = bq; gp.bias[1] = bk; gp.bias[2] = bv;
  gp.Cb[0] = qb; gp.Cb[1] = kb; gp.Cb[2] = vtb;
  gp.Cf[0] = nullptr; gp.Cf[1] = nullptr; gp.Cf[2] = nullptr;
  gp.scale[0] = 0.125f * 1.44269504f; gp.scale[1] = 1.f; gp.scale[2] = 1.f;
  gp.vt[0] = 0; gp.vt[1] = 0; gp.vt[2] = 1;
  gemm_bt_k<true><<<dim3(MR / 128, DIMSZ / 128, 3), 256, 0, stream>>>(gp);

  // 3) fused attention
  attn_k<<<dim3(SEQ / 128, BATCH * NHEADS), 512, 0, stream>>>(qb, kb, vtb, ob);

  // 4) output projection (fp32 out + bias)
  GemmArgs go;
  go.A[0] = ob; go.A[1] = ob; go.A[2] = ob;
  go.Bt[0] = wob; go.Bt[1] = wob; go.Bt[2] = wob;
  go.bias[0] = bo; go.bias[1] = bo; go.bias[2] = bo;
  go.Cb[0] = nullptr; go.Cb[1] = nullptr; go.Cb[2] = nullptr;
  go.Cf[0] = out; go.Cf[1] = out; go.Cf[2] = out;
  go.scale[0] = 1.f; go.scale[1] = 1.f; go.scale[2] = 1.f;
  go.vt[0] = 0; go.vt[1] = 0; go.vt[2] = 0;
  gemm_bt_k<false><<<dim3(MR / 128, DIMSZ / 128, 1), 256, 0, stream>>>(go);
}

// Round 11
// 390.523 us; speedup vs baseline: 1.1042x; 1.1042x over previous
//
#include <hip/hip_runtime.h>
#include <cstdint>
#include <cstddef>

#define NHEADS 16
#define HD 64
#define SEQ 2048
#define BATCH 4
#define DIMSZ 1024
#define MR (BATCH * SEQ) /* 8192 */

typedef __attribute__((ext_vector_type(8))) short short8;
typedef __attribute__((ext_vector_type(4))) short short4v;
typedef __attribute__((ext_vector_type(4))) float f32x4;

typedef __attribute__((address_space(1))) const unsigned int as1_u32;
typedef __attribute__((address_space(3))) unsigned int as3_u32;

__device__ __forceinline__ unsigned short f2bf(float x) {
  union { float f; unsigned int u; } v; v.f = x;
  unsigned int r = v.u + 0x7FFFu + ((v.u >> 16) & 1u);
  return (unsigned short)(r >> 16);
}

// native base-2 exp: v_exp_f32 (D = 2^S0). Register-only asm (no mem hazard).
__device__ __forceinline__ float exp2fast(float x) {
  float r;
  asm("v_exp_f32 %0, %1" : "=v"(r) : "v"(x));
  return r;
}

__device__ __forceinline__ f32x4 mfma16(short8 a, short8 b, f32x4 c) {
  return __builtin_amdgcn_mfma_f32_16x16x32_bf16(a, b, c, 0, 0, 0);
}

__device__ __forceinline__ void gload_lds16(const void* g, void* l) {
  __builtin_amdgcn_global_load_lds((as1_u32*)g, (as3_u32*)l, 16, 0, 0);
}

// XOR swizzle for 128B-row LDS tiles (bits 4-6; involution).
__device__ __forceinline__ int swzfn(int r) { return ((r ^ (r >> 3)) & 7) << 4; }

// ---------------- fp32 -> bf16 convert ----------------
struct Cvt7 {
  const float* s[7];
  unsigned short* d[7];
  int n4[7];
};

__global__ __launch_bounds__(256) void cvt7_k(Cvt7 a) {
  const int t = blockIdx.y;
  const float4* s = (const float4*)a.s[t];
  ushort4* d = (ushort4*)a.d[t];
  const int n4 = a.n4[t];
  for (int i = blockIdx.x * 256 + threadIdx.x; i < n4; i += gridDim.x * 256) {
    float4 f = s[i];
    ushort4 u;
    u.x = f2bf(f.x); u.y = f2bf(f.y); u.z = f2bf(f.z); u.w = f2bf(f.w);
    d[i] = u;
  }
}

// ---------------- GEMM: C[M,N] = A[M,K] * Bt[N,K]^T + bias ----------------
// m97 structure (single-buffered; round-8 HW-verified — explicit dbuf regressed
// per round-10 bench, reproducing the m99/m100 null).
struct GemmArgs {
  const unsigned short* A[3];
  const unsigned short* Bt[3];
  const float* bias[3];
  unsigned short* Cb[3];
  float* Cf[3];
  float scale[3];
  int vt[3];  // 1 => write bf16 output transposed per-head: vt[bh][d][kv]
};

template <bool BF16OUT>
__global__ __launch_bounds__(256) void gemm_bt_k(GemmArgs g) {
  const int z = blockIdx.z;
  const unsigned short* __restrict__ A = g.A[z];
  const unsigned short* __restrict__ Bt = g.Bt[z];
  const float* __restrict__ bias = g.bias[z];

  __shared__ unsigned short As[128 * 32];
  __shared__ unsigned short Bs[128 * 32];

  const int tid = threadIdx.x;
  const int lane = tid & 63;
  const int wave = tid >> 6;
  const int bm = blockIdx.x * 128;
  const int bn = blockIdx.y * 128;
  const int wm = (wave >> 1) * 64;
  const int wn = (wave & 1) * 64;

  const int srow = wave * 16 + (lane >> 2);
  const int scol = (lane & 3) * 8;
  const unsigned short* a_src = A + (size_t)(bm + srow) * DIMSZ + scol;
  const unsigned short* b_src = Bt + (size_t)(bn + srow) * DIMSZ + scol;
  char* a_dst = (char*)As + (size_t)(wave * 16) * 64;
  char* b_dst = (char*)Bs + (size_t)(wave * 16) * 64;

  const int fr = lane & 15;
  const int fk = (lane >> 4) * 8;

  f32x4 acc[4][4];
#pragma unroll
  for (int m = 0; m < 4; m++)
#pragma unroll
    for (int n = 0; n < 4; n++) acc[m][n] = (f32x4){0.f, 0.f, 0.f, 0.f};

  for (int k0 = 0; k0 < DIMSZ; k0 += 32) {
    __syncthreads();
    gload_lds16(a_src + k0, a_dst);
    gload_lds16(a_src + (size_t)64 * DIMSZ + k0, a_dst + 64 * 64);
    gload_lds16(b_src + k0, b_dst);
    gload_lds16(b_src + (size_t)64 * DIMSZ + k0, b_dst + 64 * 64);
    __syncthreads();

    short8 af[4], bfr[4];
#pragma unroll
    for (int m = 0; m < 4; m++) af[m] = *(const short8*)&As[(wm + m * 16 + fr) * 32 + fk];
#pragma unroll
    for (int n = 0; n < 4; n++) bfr[n] = *(const short8*)&Bs[(wn + n * 16 + fr) * 32 + fk];
#pragma unroll
    for (int m = 0; m < 4; m++)
#pragma unroll
      for (int n = 0; n < 4; n++) acc[m][n] = mfma16(af[m], bfr[n], acc[m][n]);
  }

  // epilogue: C/D layout col=lane&15, row=(lane>>4)*4+j (m89/m91-verified)
  const int r4 = (lane >> 4) * 4;
  const float sc = g.scale[z];
  if (g.vt[z]) {
    // write V^T per-head: vt[(b*16+h)*64 + d][kv], 4 consecutive rows packed
    unsigned short* vtp = g.Cb[z];
#pragma unroll
    for (int n = 0; n < 4; n++) {
      const int c = bn + wn + n * 16 + fr;
      const float bv = bias[c];
#pragma unroll
      for (int m = 0; m < 4; m++) {
        const int rr = bm + wm + m * 16 + r4;
        ushort4 u;
        u.x = f2bf((acc[m][n][0] + bv) * sc);
        u.y = f2bf((acc[m][n][1] + bv) * sc);
        u.z = f2bf((acc[m][n][2] + bv) * sc);
        u.w = f2bf((acc[m][n][3] + bv) * sc);
        const size_t idx =
            ((size_t)((rr >> 11) * NHEADS + (c >> 6)) * HD + (c & 63)) * SEQ + (rr & (SEQ - 1));
        *(ushort4*)&vtp[idx] = u;
      }
    }
  } else {
#pragma unroll
    for (int n = 0; n < 4; n++) {
      const int c = bn + wn + n * 16 + fr;
      const float bv = bias[c];
#pragma unroll
      for (int m = 0; m < 4; m++) {
#pragma unroll
        for (int j = 0; j < 4; j++) {
          const int r = bm + wm + m * 16 + r4 + j;
          const float val = (acc[m][n][j] + bv) * sc;
          if (BF16OUT)
            g.Cb[z][(size_t)r * DIMSZ + c] = f2bf(val);
          else
            g.Cf[z][(size_t)r * DIMSZ + c] = val;
        }
      }
    }
  }
}

// ---------------- fused attention ----------------
// grid (SEQ/128, 64 bh), 8 waves x 16 q-rows. Swapped QK^T; online-max softmax
// in exp2 domain via NATIVE v_exp_f32 (round-10 lesson: exp2f() lowers to the
// OCML denormal-fixup path, +19%); defer-rescale THR=11 (log2); pi-permuted PV;
// K/V^T via global_load_lds (pre-swizzled source), double-buffered.
__global__ __launch_bounds__(512) void attn_k(const unsigned short* __restrict__ q,
                                              const unsigned short* __restrict__ k,
                                              const unsigned short* __restrict__ vt,
                                              unsigned short* __restrict__ o) {
  const int tid = threadIdx.x;
  const int lane = tid & 63;
  const int wave = tid >> 6;  // 0..7
  const int bh = blockIdx.y;
  const int b = bh >> 4;
  const int h = bh & 15;
  const int q0 = blockIdx.x * 128;

  __shared__ unsigned short Ks[2][64 * 64];
  __shared__ unsigned short Vs[2][64 * 64];

  const int fr = lane & 15;
  const int g4 = lane >> 4;
  const int fkb = g4 * 16;

  // Q fragments (Q pre-scaled by 0.125*log2e in the projection GEMM)
  const size_t qrow = (size_t)b * SEQ + q0 + wave * 16 + fr;
  const unsigned short* qp = q + qrow * DIMSZ + h * HD + g4 * 8;
  const short8 qa0 = *(const short8*)(qp);
  const short8 qa1 = *(const short8*)(qp + 32);

  float m_run = -1e30f, l_run = 0.f;
  f32x4 oacc[4];
#pragma unroll
  for (int n = 0; n < 4; n++) oacc[n] = (f32x4){0.f, 0.f, 0.f, 0.f};

  // loop-invariant LDS read offsets
  int koff[4][2];   // QK^T: b128 reads of K rows
  int voff[4][4];   // PV: b64 reads of V^T rows at pi-slot offsets
#pragma unroll
  for (int n = 0; n < 4; n++) {
    const int row = fr + 16 * n;
    const int swz = swzfn(row);
    koff[n][0] = (row * 128 + fkb) ^ swz;
    koff[n][1] = (row * 128 + 64 + fkb) ^ swz;
#pragma unroll
    for (int c = 0; c < 4; c++) voff[n][c] = (row * 128 + (c * 32 + 8 * g4)) ^ swz;
  }

  // staging: 8 waves x 8 rows; linear LDS dest, pre-swizzled global source
  const int klrow = lane >> 3;
  const int kcb = (lane & 7) * 16;
  const int srow = wave * 8 + klrow;  // 0..63
  const int scol = (kcb ^ swzfn(srow)) >> 1;
  const unsigned short* ksrc =
      k + (size_t)b * SEQ * DIMSZ + h * HD + (size_t)srow * DIMSZ + scol;
  const unsigned short* vsrc =
      vt + (size_t)bh * HD * SEQ + (size_t)srow * SEQ + scol;

  auto stage = [&](int t, int buf) {
    const size_t kv0 = (size_t)t * 64;
    gload_lds16(ksrc + kv0 * DIMSZ, (char*)Ks[buf] + wave * 1024);
    gload_lds16(vsrc + kv0, (char*)Vs[buf] + wave * 1024);
  };

  stage(0, 0);
  __syncthreads();
  int cur = 0;

  for (int t = 0; t < SEQ / 64; ++t) {
    if (t + 1 < SEQ / 64) stage(t + 1, cur ^ 1);

    const char* Kc = (const char*)Ks[cur];
    const char* Vc = (const char*)Vs[cur];

    // S^T = K.Q^T : lane (fr,g4) holds S[kv = 16n + 4g4 + jj][q = fr] (log2 units)
    f32x4 s[4];
#pragma unroll
    for (int n = 0; n < 4; n++) {
      const short8 kb0 = *(const short8*)(Kc + koff[n][0]);
      const short8 kb1 = *(const short8*)(Kc + koff[n][1]);
      f32x4 tacc = (f32x4){0.f, 0.f, 0.f, 0.f};
      tacc = mfma16(kb0, qa0, tacc);
      tacc = mfma16(kb1, qa1, tacc);
      s[n] = tacc;
    }

    // online softmax (log2 domain), defer-rescale when max growth <= THR
    float pm = -1e30f;
#pragma unroll
    for (int n = 0; n < 4; n++)
#pragma unroll
      for (int jj = 0; jj < 4; jj++) pm = fmaxf(pm, s[n][jj]);
    pm = fmaxf(pm, __shfl_xor(pm, 16));
    pm = fmaxf(pm, __shfl_xor(pm, 32));
    if (__any(pm > m_run + 11.0f)) {
      const float mn = fmaxf(m_run, pm);
      const float sf = exp2fast(m_run - mn);
      m_run = mn;
      l_run *= sf;
      float sfr[4];
#pragma unroll
      for (int jj = 0; jj < 4; jj++) sfr[jj] = __shfl(sf, 20 * g4 + jj);
#pragma unroll
      for (int n = 0; n < 4; n++)
#pragma unroll
        for (int jj = 0; jj < 4; jj++) oacc[n][jj] *= sfr[jj];
    }

    unsigned pu[4][2];
    float rs = 0.f;
#pragma unroll
    for (int n = 0; n < 4; n++) {
      const float p0 = exp2fast(s[n][0] - m_run);
      const float p1 = exp2fast(s[n][1] - m_run);
      const float p2 = exp2fast(s[n][2] - m_run);
      const float p3 = exp2fast(s[n][3] - m_run);
      rs += (p0 + p1) + (p2 + p3);
      pu[n][0] = (unsigned)f2bf(p0) | ((unsigned)f2bf(p1) << 16);
      pu[n][1] = (unsigned)f2bf(p2) | ((unsigned)f2bf(p3) << 16);
    }
    l_run += rs;  // per-lane partial (row-sum deferred to epilogue)

    // pi-permuted A-fragments: slot k=8*g4+e  <->  kv = (e<4 ? 4g4+e : 16+4g4+e-4)
    // (+32 for pa1) — exactly the kv values this lane already holds. No shuffles.
    union { unsigned u[4]; short8 v; } pa0, pa1;
    pa0.u[0] = pu[0][0]; pa0.u[1] = pu[0][1]; pa0.u[2] = pu[1][0]; pa0.u[3] = pu[1][1];
    pa1.u[0] = pu[2][0]; pa1.u[1] = pu[2][1]; pa1.u[2] = pu[3][0]; pa1.u[3] = pu[3][1];

    // O += P V, B-frag read at matching pi-slot offsets (two b64 per frag)
#pragma unroll
    for (int n = 0; n < 4; n++) {
      union { short4v h[2]; short8 v; } vb0, vb1;
      vb0.h[0] = *(const short4v*)(Vc + voff[n][0]);
      vb0.h[1] = *(const short4v*)(Vc + voff[n][1]);
      vb1.h[0] = *(const short4v*)(Vc + voff[n][2]);
      vb1.h[1] = *(const short4v*)(Vc + voff[n][3]);
      oacc[n] = mfma16(pa0.v, vb0.v, oacc[n]);
      oacc[n] = mfma16(pa1.v, vb1.v, oacc[n]);
    }

    __syncthreads();  // next-tile staging complete; cur buffer free
    cur ^= 1;
  }

  // epilogue: reduce l across the 4 g4 copies, then O /= l
  l_run += __shfl_xor(l_run, 16);
  l_run += __shfl_xor(l_run, 32);
  float inv[4];
#pragma unroll
  for (int jj = 0; jj < 4; jj++) inv[jj] = 1.f / __shfl(l_run, 20 * g4 + jj);
#pragma unroll
  for (int n = 0; n < 4; n++)
#pragma unroll
    for (int jj = 0; jj < 4; jj++) {
      const int row = q0 + wave * 16 + 4 * g4 + jj;
      o[((size_t)bh * SEQ + row) * HD + fr + 16 * n] = f2bf(oacc[n][jj] * inv[jj]);
    }
}

// ---------------- launcher ----------------
extern "C" void kernel_launch(void* const* d_in, const int* in_sizes, int n_in,
                              void* d_out, int out_size, void* d_ws, size_t ws_size,
                              hipStream_t stream) {
  (void)in_sizes; (void)n_in; (void)out_size; (void)ws_size;
  const float* query = (const float*)d_in[0];
  const float* key_i = (const float*)d_in[1];
  const float* value = (const float*)d_in[2];
  const float* Wq = (const float*)d_in[3];
  const float* bq = (const float*)d_in[4];
  const float* Wk = (const float*)d_in[5];
  const float* bk = (const float*)d_in[6];
  const float* Wv = (const float*)d_in[7];
  const float* bv = (const float*)d_in[8];
  const float* Wo = (const float*)d_in[9];
  const float* bo = (const float*)d_in[10];
  float* out = (float*)d_out;

  char* ws = (char*)d_ws;
  size_t off = 0;
  auto alloc = [&](size_t bytes) -> char* {
    char* p = ws + off;
    off += (bytes + 255) & ~(size_t)255;
    return p;
  };
  const size_t big = (size_t)MR * DIMSZ * 2;      // 16.78 MB
  const size_t wsz = (size_t)DIMSZ * DIMSZ * 2;   // 2.1 MB
  unsigned short* xq = (unsigned short*)alloc(big);
  unsigned short* xk = (unsigned short*)alloc(big);
  unsigned short* xv = (unsigned short*)alloc(big);
  unsigned short* wqb = (unsigned short*)alloc(wsz);
  unsigned short* wkb = (unsigned short*)alloc(wsz);
  unsigned short* wvb = (unsigned short*)alloc(wsz);
  unsigned short* wob = (unsigned short*)alloc(wsz);
  unsigned short* qb = (unsigned short*)alloc(big);
  unsigned short* kb = (unsigned short*)alloc(big);
  unsigned short* vtb = (unsigned short*)alloc(big);  // V^T per-head [bh][d][kv]
  unsigned short* ob = xq;  // xq dead after QKV GEMM

  // 1) convert inputs + weights to bf16
  Cvt7 ca;
  ca.s[0] = query; ca.d[0] = xq; ca.n4[0] = MR * DIMSZ / 4;
  ca.s[1] = key_i; ca.d[1] = xk; ca.n4[1] = MR * DIMSZ / 4;
  ca.s[2] = value; ca.d[2] = xv; ca.n4[2] = MR * DIMSZ / 4;
  ca.s[3] = Wq;    ca.d[3] = wqb; ca.n4[3] = DIMSZ * DIMSZ / 4;
  ca.s[4] = Wk;    ca.d[4] = wkb; ca.n4[4] = DIMSZ * DIMSZ / 4;
  ca.s[5] = Wv;    ca.d[5] = wvb; ca.n4[5] = DIMSZ * DIMSZ / 4;
  ca.s[6] = Wo;    ca.d[6] = wob; ca.n4[6] = DIMSZ * DIMSZ / 4;
  cvt7_k<<<dim3(1024, 7), 256, 0, stream>>>(ca);

  // 2) QKV projections (z-fused); Q pre-scaled by 0.125*log2e (exp2-domain
  //    softmax); V written transposed per-head
  GemmArgs gp;
  gp.A[0] = xq; gp.A[1] = xk; gp.A[2] = xv;
  gp.Bt[0] = wqb; gp.Bt[1] = wkb; gp.Bt[2] = wvb;
  gp.bias[0] = bq; gp.bias[1] = bk; gp.bias[2] = bv;
  gp.Cb[0] = qb; gp.Cb[1] = kb; gp.Cb[2] = vtb;
  gp.Cf[0] = nullptr; gp.Cf[1] = nullptr; gp.Cf[2] = nullptr;
  gp.scale[0] = 0.125f * 1.44269504f; gp.scale[1] = 1.f; gp.scale[2] = 1.f;
  gp.vt[0] = 0; gp.vt[1] = 0; gp.vt[2] = 1;
  gemm_bt_k<true><<<dim3(MR / 128, DIMSZ / 128, 3), 256, 0, stream>>>(gp);

  // 3) fused attention
  attn_k<<<dim3(SEQ / 128, BATCH * NHEADS), 512, 0, stream>>>(qb, kb, vtb, ob);

  // 4) output projection (fp32 out + bias)
  GemmArgs go;
  go.A[0] = ob; go.A[1] = ob; go.A[2] = ob;
  go.Bt[0] = wob; go.Bt[1] = wob; go.Bt[2] = wob;
  go.bias[0] = bo; go.bias[1] = bo; go.bias[2] = bo;
  go.Cb[0] = nullptr; go.Cb[1] = nullptr; go.Cb[2] = nullptr;
  go.Cf[0] = out; go.Cf[1] = out; go.Cf[2] = out;
  go.scale[0] = 1.f; go.scale[1] = 1.f; go.scale[2] = 1.f;
  go.vt[0] = 0; go.vt[1] = 0; go.vt[2] = 0;
  gemm_bt_k<false><<<dim3(MR / 128, DIMSZ / 128, 1), 256, 0, stream>>>(go);
}